// Round 17
// baseline (208.896 us; speedup 1.0000x reference)
//
#include <hip/hip_runtime.h>

#define TINYF 1e-8f
#define NITER 50
// EX float layout: parity0 slots [0,1024), parity1 slots [1024,2048),
// zeroR [2048,2176) (never written), trashW [2176,2304) (mid-lane dump).
// Slot s = wave*2 + side (side0 = rows 0,1 of strip; side1 = rows 10,11);
// within slot: [rowpair 2][lane16][4floats].
#define EXN 2304

__device__ __forceinline__ float bperm(int addr4, float v) {
    return __int_as_float(__builtin_amdgcn_ds_bpermute(addr4, __float_as_int(v)));
}
// lane i <- lane i-1 within 16-lane DPP row; 0 at row edge (= crop left edge)
__device__ __forceinline__ float dpp_shr1(float v) {
    return __int_as_float(__builtin_amdgcn_update_dpp(0, __float_as_int(v), 0x111, 0xf, 0xf, true));
}
// lane i <- lane i+1 within 16-lane DPP row; 0 at row edge (= crop right edge)
__device__ __forceinline__ float dpp_shl1(float v) {
    return __int_as_float(__builtin_amdgcn_update_dpp(0, __float_as_int(v), 0x101, 0xf, 0xf, true));
}

// full prep: s1 (|dx|=1 pairs) + s2 (|dx|=2 pairs) for this lane's 3 cols
#define PREPF(C0_, C1_, C2_) \
    L2 = dpp_shr1(C1_); L1 = dpp_shr1(C2_); R1 = dpp_shl1(C0_); R2 = dpp_shl1(C1_); \
    s1a = L1 + C1_; s1b = C0_ + C2_; s1c = C1_ + R1; \
    s2a = L2 + C2_; s2b = L1 + R1; s2c = C0_ + R2;
// s1-only prep (for |dy|=1 halo rows)
#define PREPS(C0_, C1_, C2_) \
    L1 = dpp_shr1(C2_); R1 = dpp_shl1(C0_); \
    s1a = L1 + C1_; s1b = C0_ + C2_; s1c = C1_ + R1;
// dy=0 row: center + |dx|=1 + |dx|=2
#define AT0(I, C0_, C1_, C2_, KA, KB, KC) \
    acc[I][0] += KA * C0_ + KB * s1a + KC * s2a; \
    acc[I][1] += KA * C1_ + KB * s1b + KC * s2b; \
    acc[I][2] += KA * C2_ + KB * s1c + KC * s2c;
// |dy|=1 row: center + |dx|=1 (e5 corner dropped)
#define AT1(I, C0_, C1_, C2_, KA, KB) \
    acc[I][0] += KA * C0_ + KB * s1a; \
    acc[I][1] += KA * C1_ + KB * s1b; \
    acc[I][2] += KA * C2_ + KB * s1c;
// |dy|=2 row: center only (e5/e8 dropped)
#define AT2(I, C0_, C1_, C2_, KA) \
    acc[I][0] += KA * C0_; \
    acc[I][1] += KA * C1_; \
    acc[I][2] += KA * C2_;

__global__ void __launch_bounds__(256)
__attribute__((amdgpu_waves_per_eu(1, 2)))
sinkhorn_q4(const float* __restrict__ hm_gt,
            const float* __restrict__ hm_pred,
            const int* __restrict__ tops,
            float* __restrict__ out) {
    __shared__ __align__(16) float EX[EXN];
    __shared__ float sred[8];

    const int t = threadIdx.x;
    const int w = t >> 6;                  // wave: strip rows 12w..12w+11
    const int l = t & 63;
    const int lr = l >> 4, c = l & 15;     // 4 bands x 3 rows, 16 col-groups x 3 cols
    const bool b0 = (lr == 0), b3 = (lr == 3);
    const bool edge = b0 || b3;
    const int upA = ((l - 16) & 63) << 2;
    const int dnA = ((l + 16) & 63) << 2;

    const int blk = blockIdx.x;            // ((bi*8+rr)*5+cc)
    const int bi = blk / 40, rr = (blk / 5) % 8, cc = blk % 5;
    const int y0 = tops[(bi * 8 + rr) * 2 + 0];
    const int x0 = tops[(bi * 8 + rr) * 2 + 1];
    const float* srcA = hm_gt + (size_t)(bi * 5 + cc) * 25600;
    const float* srcB = hm_pred + (size_t)(bi * 5 + cc) * 25600;

    // branchless exchange pointers
    const int rs = b0 ? ((w - 1) * 2 + 1) : ((w + 1) * 2 + 0);
    const bool rvalid = (b0 && w > 0) || (b3 && w < 3);
    const float* rp0 = EX + (rvalid ? rs * 128 + c * 4 : 2048 + c * 4);
    const float* rp1 = EX + (rvalid ? 1024 + rs * 128 + c * 4 : 2048 + c * 4);
    const int wslot = w * 2 + (b0 ? 0 : 1);
    float* wp0 = EX + (edge ? wslot * 128 + c * 4 : 2176 + c * 4);
    float* wp1 = EX + (edge ? 1024 + wslot * 128 + c * 4 : 2176 + c * 4);

    // ---- zero EX (zeroR must be 0; rest harmless) ----
    for (int p = t; p < EXN; p += 256) EX[p] = 0.f;

    // ---- load own 3x3 tiles of both crops; block-reduce sums ----
    float va[3][3], vb[3][3];
    float sA = 0.f, sB = 0.f;
    const int rbase = y0 + 12 * w + 3 * lr;
#pragma unroll
    for (int i = 0; i < 3; ++i) {
        const int g = (rbase + i) * 160 + x0 + 3 * c;
#pragma unroll
        for (int j = 0; j < 3; ++j) {
            const float A = srcA[g + j];
            const float B = srcB[g + j];
            va[i][j] = A; vb[i][j] = B;
            sA += A; sB += B;
        }
    }
#pragma unroll
    for (int o = 1; o < 64; o <<= 1) {
        sA += __shfl_xor(sA, o, 64);
        sB += __shfl_xor(sB, o, 64);
    }
    if (l == 0) { sred[w] = sA; sred[4 + w] = sB; }
    __syncthreads();   // also covers EX zeroing
    sA = sred[0] + sred[1] + sred[2] + sred[3];
    sB = sred[4] + sred[5] + sred[6] + sred[7];
    const float nA = 1.0f / (sA + TINYF);
    const float nB = 1.0f / (sB + TINYF);
#pragma unroll
    for (int i = 0; i < 3; ++i)
#pragma unroll
        for (int j = 0; j < 3; ++j) { va[i][j] *= nA; vb[i][j] *= nB; }

    // Gibbs weights (same expressions as before -> same rounding)
    const float e10 = expf(-1.0f / 0.1f);
    const float e2  = expf(-sqrtf(2.0f) / 0.1f);
    const float e20 = expf(-2.0f / 0.1f);

    float xu[3][3], xv[3][3], acc[3][3];
    const float u0 = 1.0f / 2304.0f;
#pragma unroll
    for (int i = 0; i < 3; ++i)
#pragma unroll
        for (int j = 0; j < 3; ++j) xu[i][j] = u0;

    // publish u0 boundary rows into parity-0 slots (mid lanes dump to trash)
    *(float4*)(wp0)      = make_float4(u0, u0, u0, 0.f);
    *(float4*)(wp0 + 64) = make_float4(u0, u0, u0, 0.f);
    __syncthreads();

    // 13-tap conv: vertical halos via bperm (bands) / EX (wave boundary, rpo);
    // crop top/bottom rows read zeroR. Horizontal via DPP bound_ctrl (crop edges).
    auto conv = [&](const float (&x)[3][3], const float* rpo,
                    float K00, float K01, float K02,
                    float K10, float K11, float K20) {
        const float4 q0 = *(const float4*)(rpo);
        const float4 q1 = *(const float4*)(rpo + 64);
        float tA[3], tB[3], tC[3], tD[3];
#pragma unroll
        for (int j = 0; j < 3; ++j) {
            tA[j] = bperm(upA, x[1][j]);   // row -2 candidate (lane-16 row 1)
            tB[j] = bperm(upA, x[2][j]);   // row -1
            tC[j] = bperm(dnA, x[0][j]);   // row  3
            tD[j] = bperm(dnA, x[1][j]);   // row  4
        }
#pragma unroll
        for (int i = 0; i < 3; ++i)
#pragma unroll
            for (int j = 0; j < 3; ++j) acc[i][j] = 0.f;

        float L1, L2, R1, R2, s1a, s1b, s1c, s2a, s2b, s2c;
        // own rows first (no DS dependence -> hides bperm/LDS latency)
        PREPF(x[0][0], x[0][1], x[0][2])
        AT0(0, x[0][0], x[0][1], x[0][2], K00, K01, K02)
        AT1(1, x[0][0], x[0][1], x[0][2], K10, K11)
        AT2(2, x[0][0], x[0][1], x[0][2], K20)
        PREPF(x[1][0], x[1][1], x[1][2])
        AT1(0, x[1][0], x[1][1], x[1][2], K10, K11)
        AT0(1, x[1][0], x[1][1], x[1][2], K00, K01, K02)
        AT1(2, x[1][0], x[1][1], x[1][2], K10, K11)
        PREPF(x[2][0], x[2][1], x[2][2])
        AT2(0, x[2][0], x[2][1], x[2][2], K20)
        AT1(1, x[2][0], x[2][1], x[2][2], K10, K11)
        AT0(2, x[2][0], x[2][1], x[2][2], K00, K01, K02)

        // resolve halos
        float hA[3], hB[3], hC[3], hD[3];
        const float qv0[3] = {q0.x, q0.y, q0.z};
        const float qv1[3] = {q1.x, q1.y, q1.z};
#pragma unroll
        for (int j = 0; j < 3; ++j) {
            hA[j] = b0 ? qv0[j] : tA[j];
            hB[j] = b0 ? qv1[j] : tB[j];
            hC[j] = b3 ? qv0[j] : tC[j];
            hD[j] = b3 ? qv1[j] : tD[j];
        }
        PREPS(hB[0], hB[1], hB[2])          // row -1
        AT1(0, hB[0], hB[1], hB[2], K10, K11)
        AT2(1, hB[0], hB[1], hB[2], K20)
        AT2(0, hA[0], hA[1], hA[2], K20)    // row -2 (center tap only)
        PREPS(hC[0], hC[1], hC[2])          // row 3
        AT2(1, hC[0], hC[1], hC[2], K20)
        AT1(2, hC[0], hC[1], hC[2], K10, K11)
        AT2(2, hD[0], hD[1], hD[2], K20)    // row 4 (center tap only)
    };

    // publish boundary rows of field y (b0: rows 0,1; b3: rows 1,2), then sync
    auto publish = [&](const float (&y)[3][3], float* wpo) {
        const float f0 = b0 ? y[0][0] : y[1][0];
        const float f1 = b0 ? y[0][1] : y[1][1];
        const float f2 = b0 ? y[0][2] : y[1][2];
        const float g0 = b0 ? y[1][0] : y[2][0];
        const float g1 = b0 ? y[1][1] : y[2][1];
        const float g2 = b0 ? y[1][2] : y[2][2];
        *(float4*)(wpo)      = make_float4(f0, f1, f2, 0.f);
        *(float4*)(wpo + 64) = make_float4(g0, g1, g2, 0.f);
        __syncthreads();
    };

    // ---- Sinkhorn iterations: 2 barriers/iter on a 4-wave block ----
#pragma unroll 1
    for (int it = 0; it < NITER; ++it) {
        conv(xu, rp0, 1.0f, e10, e20, e10, e2, e20);
#pragma unroll
        for (int i = 0; i < 3; ++i)
#pragma unroll
            for (int j = 0; j < 3; ++j)
                xv[i][j] = vb[i][j] * __builtin_amdgcn_rcpf(acc[i][j] + TINYF);
        publish(xv, wp1);

        conv(xv, rp1, 1.0f, e10, e20, e10, e2, e20);
#pragma unroll
        for (int i = 0; i < 3; ++i)
#pragma unroll
            for (int j = 0; j < 3; ++j)
                xu[i][j] = va[i][j] * __builtin_amdgcn_rcpf(acc[i][j] + TINYF);
        publish(xu, wp0);
    }

    // ---- loss: (u @ M) . v, M = K .* dist (center 0; e5/e8 taps dropped) ----
    const float s2f = sqrtf(2.0f);
    const float m01 = e10, m02 = e20 * 2.0f, m11 = e2 * s2f;
    conv(xu, rp0, 0.0f, m01, m02, m01, m11, m02);
    float lsum = 0.f;
#pragma unroll
    for (int i = 0; i < 3; ++i)
#pragma unroll
        for (int j = 0; j < 3; ++j)
            lsum += acc[i][j] * xv[i][j];

#pragma unroll
    for (int o = 1; o < 64; o <<= 1) lsum += __shfl_xor(lsum, o, 64);
    if (l == 0) sred[w] = lsum;
    __syncthreads();
    if (t == 0) atomicAdd(out, sred[0] + sred[1] + sred[2] + sred[3]);
}

extern "C" void kernel_launch(void* const* d_in, const int* in_sizes, int n_in,
                              void* d_out, int out_size, void* d_ws, size_t ws_size,
                              hipStream_t stream) {
    (void)in_sizes; (void)n_in; (void)out_size; (void)d_ws; (void)ws_size;
    const float* hm_gt = (const float*)d_in[0];
    const float* hm_pred = (const float*)d_in[1];
    const int* tops = (const int*)d_in[2];
    float* out = (float*)d_out;

    hipMemsetAsync(out, 0, sizeof(float), stream);
    sinkhorn_q4<<<dim3(640), dim3(256), 0, stream>>>(hm_gt, hm_pred, tops, out);
}